// Round 9
// baseline (145.835 us; speedup 1.0000x reference)
//
#include <hip/hip_runtime.h>
#include <hip/hip_bf16.h>
#include <math.h>

// EntropyInvarianceAttention: out = softmax(c * Q^T K) V^T per (b,h),
// c = ln(k_length[b]) / (8*ln(20)); q,k,v are (B, 512, 2048) fp32, l contiguous.
//
// R15 = R14 resubmitted verbatim (R8 bench round died in the container broker
// before compiling; no evidence was produced, so the phase-domain experiment
// is still pending).
//
// R14: more independent barrier domains per SIMD (attn's measured profile:
// MfmaUtil 23% + VALUBusy 43% + ~34% both-idle from 2 barrier-locked
// waves/SIMD; three structural rewrites never touched this).
//  - q-tile 64, 128-thr blocks (2 waves of 32 q), grid 1024 = 4 blocks/CU:
//    each SIMD now hosts 2 waves from DIFFERENT blocks (independent phase
//    domains, 4 domains/CU) -> QK/exp/PV phases of co-resident waves
//    interleave instead of starving the other pipe.
//  - LDS 24 KB (K-only 3-stage): V via R11-proven global b128 register
//    double-buffer (Vt3 layout unchanged; same element addressing as R12's
//    LDS reads, global instead). 4 x 24 KB = 96 KB <= 160 ✓.
//  - Sync: R12 3-stage K skeleton with DMA(kt+2), but ALL waits vmcnt(0)
//    (R11-proven: full drain + barrier per iter = safe by construction;
//    every load was issued a full iteration before its drain -> ~free).
//  - Per-wave compute byte-identical to R12: 16 mfma_32x32x16/tile, exp,
//    cvt_pk+permlane32 P repack, VALU lsum, same K/Q/V fragment layouts.
// Prep: R13 fused single-pass version (unchanged).

typedef __attribute__((ext_vector_type(8))) short short8_t;
typedef __attribute__((ext_vector_type(4))) short short4_t;
typedef __attribute__((ext_vector_type(4))) float float4_t;
typedef __attribute__((ext_vector_type(16))) float float16_t;

#define SEQ   2048
#define NBH   32
#define NKT   32

__device__ __forceinline__ unsigned f2bf2u(float a, float b) {
#if __has_builtin(__builtin_amdgcn_cvt_pk_bf16_f32)
  typedef __bf16 bf16x2_t __attribute__((ext_vector_type(2)));
  union { bf16x2_t v; unsigned u; } cv;
  cv.v = __builtin_amdgcn_cvt_pk_bf16_f32(a, b);
  return cv.u;
#else
  union { float f; unsigned u; } x, y;
  x.f = a; y.f = b;
  unsigned ra = x.u + 0x7fffu + ((x.u >> 16) & 1u);
  unsigned rb = y.u + 0x7fffu + ((y.u >> 16) & 1u);
  return (ra >> 16) | (rb & 0xffff0000u);
#endif
}

__device__ __forceinline__ short f2bf1(float a) {
  return (short)(f2bf2u(a, a) & 0xffffu);
}

__device__ __forceinline__ float fast_exp2(float x) {
#if __has_builtin(__builtin_amdgcn_exp2f)
  return __builtin_amdgcn_exp2f(x);
#else
  return exp2f(x);
#endif
}

__device__ __forceinline__ void gld16(const void* g, void* l) {
  __builtin_amdgcn_global_load_lds(
      (const __attribute__((address_space(1))) void*)g,
      (__attribute__((address_space(3))) void*)l, 16, 0, 0);
}

__device__ __forceinline__ float4_t mfma32(short8_t a, short8_t b, float4_t c) {
  return __builtin_amdgcn_mfma_f32_16x16x32_bf16(a, b, c, 0, 0, 0);
}

__device__ __forceinline__ float16_t mfma3232(short8_t a, short8_t b, float16_t c) {
  return __builtin_amdgcn_mfma_f32_32x32x16_bf16(a, b, c, 0, 0, 0);
}

// lane<32/lane>=32 half exchange: a' = [a_lo|b_lo], b' = [a_hi|b_hi]
__device__ __forceinline__ void plswap(unsigned& a, unsigned& b, int hi) {
#if __has_builtin(__builtin_amdgcn_permlane32_swap)
  typedef __attribute__((ext_vector_type(2))) unsigned uint2_t;
  uint2_t r = __builtin_amdgcn_permlane32_swap(a, b, false, false);
  a = r[0]; b = r[1];
#else
  const unsigned sa = (unsigned)__shfl_xor((int)a, 32);
  const unsigned sb = (unsigned)__shfl_xor((int)b, 32);
  const unsigned an = hi ? sb : a;
  const unsigned bn = hi ? b : sa;
  a = an; b = bn;
#endif
}

// ---------------- fused pre-pass (R13): one block per (bh,kt) ----------
// K -> Kt2[bh][kt][ch(8)][lr(64)][8]: out[ch*512+lr*8+j] = K[d=ch*8+j][k=lr]
// V -> Vt3[bh][kt][kc(8)][d(64)][8]:  out[(kc*64+d)*8+j] = V[d][k=kc*8+j]
#define PST 68
__global__ __launch_bounds__(256, 8)
void eia_prep_kernel(const float* __restrict__ kg, const float* __restrict__ vg,
                     unsigned short* __restrict__ Kt2, unsigned short* __restrict__ Vt2) {
  __shared__ __align__(16) short T[64 * PST];
  const int bh = blockIdx.x >> 5;
  const int kt = blockIdx.x & 31;
  const int t  = threadIdx.x;

  // ---- K phase: float4 loads along k, scatter bf16 to T[k][d] ----
  {
    const int dr = t >> 4;          // 0..15
    const int kq = (t & 15) * 4;    // 0,4,..,60
#pragma unroll
    for (int i = 0; i < 4; ++i) {
      const int d = i * 16 + dr;
      const float4_t f = *(const float4_t*)
          &kg[((size_t)bh * 64 + d) * SEQ + (size_t)(kt * 64 + kq)];
      T[(kq + 0) * PST + d] = f2bf1(f[0]);
      T[(kq + 1) * PST + d] = f2bf1(f[1]);
      T[(kq + 2) * PST + d] = f2bf1(f[2]);
      T[(kq + 3) * PST + d] = f2bf1(f[3]);
    }
  }
  __syncthreads();
  // K writeout (byte-identical to proven layout)
  {
    unsigned short* outt = Kt2 + (size_t)(bh * 32 + kt) * 4096;
#pragma unroll
    for (int rep = 0; rep < 2; ++rep) {
      const int id2 = rep * 256 + t;
      const int lr = id2 & 63, ch = id2 >> 6;
      union { short8_t v; short4_t h[2]; } o;
      o.h[0] = *(const short4_t*)&T[lr * PST + ch * 8];
      o.h[1] = *(const short4_t*)&T[lr * PST + ch * 8 + 4];
      *(short8_t*)&outt[ch * 512 + lr * 8] = o.v;
    }
  }
  __syncthreads();  // K reads of T done before V overwrites

  // ---- V phase: float4 loads along k into T[d][k] (proven pattern) ----
#pragma unroll
  for (int rep = 0; rep < 4; ++rep) {
    const int id2 = rep * 256 + t;
    const int d = id2 >> 4, l4 = (id2 & 15) * 4;
    const float4_t f = *(const float4_t*)
        &vg[((size_t)bh * 64 + d) * SEQ + (size_t)(kt * 64 + l4)];
    union { short4_t s; unsigned u[2]; } p;
    p.u[0] = f2bf2u(f[0], f[1]);
    p.u[1] = f2bf2u(f[2], f[3]);
    *(short4_t*)&T[d * PST + l4] = p.s;
  }
  __syncthreads();
  // Vt3 writeout (byte-identical to R12)
  {
    unsigned short* outt = Vt2 + (size_t)(bh * 32 + kt) * 4096;
#pragma unroll
    for (int rep = 0; rep < 2; ++rep) {
      const int c = rep * 256 + t;
      const int kc = c >> 6, d = c & 63;
      union { short8_t v; short4_t h[2]; } o;
      o.h[0] = *(const short4_t*)&T[d * PST + kc * 8];
      o.h[1] = *(const short4_t*)&T[d * PST + kc * 8 + 4];
      *(short8_t*)&outt[c * 8] = o.v;
    }
  }
}

// ---------------- main fused attention (R14: 64-q blocks, V-in-reg) ----------
// LDS (shorts): K stages [0,4096)|[4096,8192)|[8192,12288)  (24 KB total)
// Q staging overlays [0, 4352) before the first DMA.
__global__ __launch_bounds__(128, 2)
void eia_attn_kernel(const float* __restrict__ qg,
                     const unsigned short* __restrict__ Kt2,
                     const unsigned short* __restrict__ Vt2,
                     const int* __restrict__ klen,
                     float* __restrict__ outg) {
  __shared__ __align__(16) short SM[12288];

  const int tid   = threadIdx.x;
  const int bh    = blockIdx.x & 31;   // XCD = bh%8; 1024 blocks = 4/CU
  const int qt    = blockIdx.x >> 5;   // 0..31
  const int q0    = qt * 64;
  const int qw    = tid >> 6;          // wave 0..1: q-subtile qw*32
  const int lane  = tid & 63;
  const int l31   = lane & 31;
  const int hi    = lane >> 5;

  const float c = (1.4426950408889634f / (8.0f * 2.9957322735539909f)) *
                  logf((float)klen[bh >> 3]);
  const size_t qb = (size_t)bh * 64 * SEQ;

  // ---- Q stage: fp32 global -> SM[q][d] bf16 (stride 68), c folded ----
#pragma unroll
  for (int rep = 0; rep < 8; ++rep) {
    const int id = rep * 128 + tid;       // 0..1023
    const int d  = id >> 4;               // 0..63
    const int q4 = (id & 15) * 4;         // 0..60
    const float4_t f = *(const float4_t*)&qg[qb + (size_t)d * SEQ + (size_t)(q0 + q4)];
    SM[(q4 + 0) * 68 + d] = f2bf1(c * f[0]);
    SM[(q4 + 1) * 68 + d] = f2bf1(c * f[1]);
    SM[(q4 + 2) * 68 + d] = f2bf1(c * f[2]);
    SM[(q4 + 3) * 68 + d] = f2bf1(c * f[3]);
  }
  __syncthreads();

  // Q B-fragments (32x32x16 B-layout): B[d=s*16+hi*8+j][q=l31], s=0..3
  short8_t qfrag[4];
#pragma unroll
  for (int s = 0; s < 4; ++s) {
    const short* qp = &SM[(qw * 32 + l31) * 68 + s * 16 + hi * 8];
    const short4_t lo = *(const short4_t*)qp;
    const short4_t hh = *(const short4_t*)(qp + 4);
    qfrag[s] = short8_t{lo[0], lo[1], lo[2], lo[3], hh[0], hh[1], hh[2], hh[3]};
  }
  __syncthreads();  // Q reads done before DMA overwrites SM

  // ---- K DMA: tile = 8 x 1KB instrs over 2 waves = 4/wave ----
  const char* ksrc = (const char*)Kt2 + (size_t)bh * NKT * 8192 + (4 * qw) * 1024 + lane * 16;
  short* const kdst = &SM[(4 * qw) * 512];     // + stage*4096 (HW adds lane*16B)

  // per-lane invariant fragment offset (shorts): hi*512 + l31*8
  const int lofs = hi * 512 + l31 * 8;
  const short* const kfp = &SM[lofs];          // + koff + kbhalf*256 + s*1024

  // ---- V global base (Vt3 layout): same element addressing as R12's LDS
  // reads, as global bytes: tile + hi*1024 + l31*16 + dt*512 + ks*2048 ----
  const char* const vgl = (const char*)Vt2 + (size_t)bh * NKT * 8192 +
                          hi * 1024 + l31 * 16;

  const float16_t z16 = {0.f,0.f,0.f,0.f,0.f,0.f,0.f,0.f,
                         0.f,0.f,0.f,0.f,0.f,0.f,0.f,0.f};
  float16_t oacc0 = z16, oacc1 = z16;   // dt = 0,1
  float ls = 0.f;

  // V register double-buffers (compile-time ping-pong; rule #20)
  short8_t vA[8], vB[8];   // [dt*4 + ks]

  // ---- prologue: DMA K tiles 0,1 -> stages 0,1; V(0) -> vA ----
#pragma unroll
  for (int i = 0; i < 4; ++i) gld16(ksrc + i * 1024, kdst + i * 512);
#pragma unroll
  for (int i = 0; i < 4; ++i) gld16(ksrc + 8192 + i * 1024, kdst + 4096 + i * 512);
#pragma unroll
  for (int dt = 0; dt < 2; ++dt)
#pragma unroll
    for (int ks = 0; ks < 4; ++ks)
      vA[dt * 4 + ks] = *(const short8_t*)(vgl + dt * 512 + ks * 2048);

  int  sc = 0;              // stage (shorts offset/4096) of current tile
  int  sn = 2;              // stage of tile kt+2
  size_t gsrc = 2 * 8192;   // byte offset of K tile kt+2

  // Full drain + barrier each iter (R11-proven safe-by-construction):
  // K(kt) was issued 2 iters ago, K(kt+1) and V(kt) 1 iter ago -> drain ~free.
#define EIA_BODY(KT, VC, VN)                                                  \
  do {                                                                        \
    asm volatile("s_waitcnt vmcnt(0)" ::: "memory");                          \
    asm volatile("s_barrier" ::: "memory");                                   \
    if ((KT) < NKT - 2) {                                                     \
      const int so = sn * 4096;                                               \
      _Pragma("unroll")                                                       \
      for (int i = 0; i < 4; ++i)                                             \
        gld16(ksrc + gsrc + i * 1024, kdst + so + i * 512);                   \
      gsrc += 8192;                                                           \
      sn = (sn == 2) ? 0 : sn + 1;                                            \
    }                                                                         \
    if ((KT) < NKT - 1) {                                                     \
      const char* vp = vgl + (size_t)((KT) + 1) * 8192;                       \
      _Pragma("unroll")                                                       \
      for (int dt = 0; dt < 2; ++dt)                                          \
        _Pragma("unroll")                                                     \
        for (int ks = 0; ks < 4; ++ks)                                        \
          VN[dt * 4 + ks] = *(const short8_t*)(vp + dt * 512 + ks * 2048);    \
    }                                                                         \
    const int koff = sc * 4096;                                               \
    sc = (sc == 2) ? 0 : sc + 1;                                              \
    const short* const kb_ = kfp + koff;                                      \
    /* S^T = K^T * Q : 2 kb-halves x 4 chained mfma_32x32x16 */               \
    float16_t s0 = z16, s1 = z16;                                             \
    _Pragma("unroll")                                                         \
    for (int s = 0; s < 4; ++s)                                               \
      s0 = mfma3232(*(const short8_t*)(kb_ + s * 1024), qfrag[s], s0);        \
    _Pragma("unroll")                                                         \
    for (int s = 0; s < 4; ++s)                                               \
      s1 = mfma3232(*(const short8_t*)(kb_ + 256 + s * 1024), qfrag[s], s1);  \
    /* exp + lsum + P repack (C->B via cvt_pk + permlane32_swap) */           \
    union pfu { short8_t s8; unsigned u[4]; };                                \
    pfu pf[4];                                                                \
    _Pragma("unroll")                                                         \
    for (int kb = 0; kb < 2; ++kb) {                                          \
      float e[16];                                                            \
      _Pragma("unroll")                                                       \
      for (int r = 0; r < 16; ++r)                                            \
        e[r] = fast_exp2(kb == 0 ? s0[r] : s1[r]);                            \
      ls += (((e[0] + e[1]) + (e[2] + e[3])) +                                \
             ((e[4] + e[5]) + (e[6] + e[7]))) +                               \
            (((e[8] + e[9]) + (e[10] + e[11])) +                              \
             ((e[12] + e[13]) + (e[14] + e[15])));                            \
      _Pragma("unroll")                                                       \
      for (int ksl = 0; ksl < 2; ++ksl) {                                     \
        const int b = ksl * 8;                                                \
        unsigned a02 = f2bf2u(e[b + 0], e[b + 1]);                            \
        unsigned b02 = f2bf2u(e[b + 4], e[b + 5]);                            \
        unsigned a13 = f2bf2u(e[b + 2], e[b + 3]);                            \
        unsigned b13 = f2bf2u(e[b + 6], e[b + 7]);                            \
        plswap(a02, b02, hi);                                                 \
        plswap(a13, b13, hi);                                                 \
        pf[kb * 2 + ksl].u[0] = a02;                                          \
        pf[kb * 2 + ksl].u[1] = a13;                                          \
        pf[kb * 2 + ksl].u[2] = b02;                                          \
        pf[kb * 2 + ksl].u[3] = b13;                                          \
      }                                                                       \
    }                                                                         \
    /* O^T += V * P^T from registers: 2 dt x 4 chained mfma_32x32x16 */       \
    _Pragma("unroll")                                                         \
    for (int ks = 0; ks < 4; ++ks)                                            \
      oacc0 = mfma3232(VC[ks], pf[ks].s8, oacc0);                             \
    _Pragma("unroll")                                                         \
    for (int ks = 0; ks < 4; ++ks)                                            \
      oacc1 = mfma3232(VC[4 + ks], pf[ks].s8, oacc1);                         \
  } while (0)

  for (int kt = 0; kt < NKT; kt += 2) {
    EIA_BODY(kt,     vA, vB);
    EIA_BODY(kt + 1, vB, vA);
  }
#undef EIA_BODY

  // ---- epilogue: lsum cross-half add, normalize (lane's q = l31), store ----
  const float lst = ls + __shfl_xor(ls, 32);
  const float inv = 1.0f / lst;
  const size_t ob = qb + (size_t)(q0 + qw * 32 + l31);
#pragma unroll
  for (int r = 0; r < 16; ++r) {
    const int drow = (r & 3) + 8 * (r >> 2) + 4 * hi;
    outg[ob + (size_t)(drow) * SEQ]      = oacc0[r] * inv;
    outg[ob + (size_t)(drow + 32) * SEQ] = oacc1[r] * inv;
  }
}

// ---------------- fallback (ws too small): R2-style, known-good ----------------
#define DPAD  72
#define PPAD  68
__global__ __launch_bounds__(256, 5)
void eia_attn_fb(const float* __restrict__ qg, const float* __restrict__ kg,
                 const float* __restrict__ vg, const int* __restrict__ klen,
                 float* __restrict__ outg) {
  __shared__ __align__(16) short QPs[64 * DPAD];
  __shared__ __align__(16) short Ksf[64 * DPAD];
  __shared__ __align__(16) short Vsf[64 * DPAD];

  const int tid  = threadIdx.x;
  const int bh   = blockIdx.x & 31;
  const int qt   = blockIdx.x >> 5;
  const int q0   = qt * 64;
  const int w    = tid >> 6;
  const int lane = tid & 63;
  const int quad = lane >> 4;
  const int l16  = lane & 15;

  const size_t base = (size_t)bh * 64 * SEQ;
  const float c = (1.4426950408889634f / (8.0f * 2.9957322735539909f)) *
                  logf((float)klen[bh >> 3]);

#pragma unroll
  for (int it = 0; it < 2; ++it) {
    const int e = it * 4 + w;
    float f[8];
#pragma unroll
    for (int j = 0; j < 8; ++j)
      f[j] = c * qg[base + (size_t)(e * 8 + j) * SEQ + (size_t)(q0 + lane)];
    union { short8_t s8; unsigned u[4]; } t;
#pragma unroll
    for (int j = 0; j < 4; ++j) t.u[j] = f2bf2u(f[2 * j], f[2 * j + 1]);
    *(short8_t*)&QPs[lane * DPAD + e * 8] = t.s8;
  }
  __syncthreads();

  short8_t qfrag[2];
#pragma unroll
  for (int s = 0; s < 2; ++s)
    qfrag[s] = *(const short8_t*)&QPs[(w * 16 + l16) * DPAD + s * 32 + quad * 8];

  float4_t oacc[4];
#pragma unroll
  for (int t = 0; t < 4; ++t) { oacc[t][0] = 0.f; oacc[t][1] = 0.f; oacc[t][2] = 0.f; oacc[t][3] = 0.f; }
  float lsumv[4] = {0.f, 0.f, 0.f, 0.f};
  const int pbase = w * (16 * DPAD);

  for (int kt = 0; kt < NKT; ++kt) {
    const int k0 = kt * 64;
#pragma unroll
    for (int it = 0; it < 2; ++it) {
      float f[8];
#pragma unroll
      for (int j = 0; j < 8; ++j)
        f[j] = kg[base + (size_t)((it * 4 + w) * 8 + j) * SEQ + (size_t)(k0 + lane)];
      union { short8_t s8; unsigned u[4]; } t;
#pragma unroll
      for (int j = 0; j < 4; ++j) t.u[j] = f2bf2u(f[2 * j], f[2 * j + 1]);
      *(short8_t*)&Ksf[lane * DPAD + (it * 4 + w) * 8] = t.s8;
    }
#pragma unroll
    for (int it = 0; it < 4; ++it) {
      const int d = it * 16 + (w << 2) + (lane >> 4);
      const float4_t vv = *(const float4_t*)&vg[base + (size_t)d * SEQ + (size_t)(k0 + ((lane & 15) << 2))];
      union { short4_t s4; unsigned u[2]; } t;
      t.u[0] = f2bf2u(vv[0], vv[1]);
      t.u[1] = f2bf2u(vv[2], vv[3]);
      *(short4_t*)&Vsf[d * DPAD + ((lane & 15) << 2)] = t.s4;
    }
    __syncthreads();

    float4_t sacc[4];
#pragma unroll
    for (int t = 0; t < 4; ++t) { sacc[t][0] = 0.f; sacc[t][1] = 0.f; sacc[t][2] = 0.f; sacc[t][3] = 0.f; }
#pragma unroll
    for (int t = 0; t < 4; ++t)
#pragma unroll
      for (int s = 0; s < 2; ++s) {
        const short8_t bf = *(const short8_t*)&Ksf[(t * 16 + l16) * DPAD + s * 32 + quad * 8];
        sacc[t] = mfma32(qfrag[s], bf, sacc[t]);
      }

#pragma unroll
    for (int r = 0; r < 4; ++r) {
      const float p0 = fast_exp2(sacc[0][r]);
      const float p1 = fast_exp2(sacc[1][r]);
      const float p2 = fast_exp2(sacc[2][r]);
      const float p3 = fast_exp2(sacc[3][r]);
      lsumv[r] += (p0 + p1) + (p2 + p3);
      const int prow = pbase + (quad * 4 + r) * PPAD + l16;
      QPs[prow +  0] = f2bf1(p0);
      QPs[prow + 16] = f2bf1(p1);
      QPs[prow + 32] = f2bf1(p2);
      QPs[prow + 48] = f2bf1(p3);
    }

#pragma unroll
    for (int s = 0; s < 2; ++s) {
      const short* pr = &QPs[pbase + l16 * PPAD + s * 32 + quad * 8];
      const short4_t plo = *(const short4_t*)pr;
      const short4_t phi = *(const short4_t*)(pr + 4);
      const short8_t pfv = {plo[0], plo[1], plo[2], plo[3], phi[0], phi[1], phi[2], phi[3]};
#pragma unroll
      for (int t = 0; t < 4; ++t) {
        const short8_t vf = *(const short8_t*)&Vsf[(t * 16 + l16) * DPAD + s * 32 + quad * 8];
        oacc[t] = mfma32(pfv, vf, oacc[t]);
      }
    }
    __syncthreads();
  }

  float inv[4];
#pragma unroll
  for (int r = 0; r < 4; ++r) {
    float v = lsumv[r];
    v += __shfl_xor(v, 1);
    v += __shfl_xor(v, 2);
    v += __shfl_xor(v, 4);
    v += __shfl_xor(v, 8);
    inv[r] = 1.0f / v;
  }
#pragma unroll
  for (int t = 0; t < 4; ++t)
#pragma unroll
    for (int r = 0; r < 4; ++r)
      outg[base + (size_t)(t * 16 + l16) * SEQ +
           (size_t)(q0 + w * 16 + quad * 4 + r)] = oacc[t][r] * inv[r];
}

extern "C" void kernel_launch(void* const* d_in, const int* in_sizes, int n_in,
                              void* d_out, int out_size, void* d_ws, size_t ws_size,
                              hipStream_t stream) {
  const float* q  = (const float*)d_in[0];
  const float* k  = (const float*)d_in[1];
  const float* v  = (const float*)d_in[2];
  const int*   kl = (const int*)d_in[3];
  float* out = (float*)d_out;

  const size_t TEN  = (size_t)NBH * SEQ * 64;
  const size_t need = 2 * TEN * sizeof(unsigned short);  // 16.8 MB

  if (ws_size >= need) {
    unsigned short* Kt2 = (unsigned short*)d_ws;
    unsigned short* Vt2 = Kt2 + TEN;
    eia_prep_kernel<<<1024, 256, 0, stream>>>(k, v, Kt2, Vt2);
    eia_attn_kernel<<<1024, 128, 0, stream>>>(q, Kt2, Vt2, kl, out);
  } else {
    eia_attn_fb<<<1024, 256, 0, stream>>>(q, k, v, kl, out);
  }
}

// Round 10
// 140.085 us; speedup vs baseline: 1.0410x; 1.0410x over previous
//
#include <hip/hip_runtime.h>
#include <hip/hip_bf16.h>
#include <math.h>

// EntropyInvarianceAttention: out = softmax(c * Q^T K) V^T per (b,h),
// c = ln(k_length[b]) / (8*ln(20)); q,k,v are (B, 512, 2048) fp32, l contiguous.
//
// R16 = R12 (best verified: attn 58.4us; 512x256, 32x32x16 MFMA path) with
// tile-PAIR barrier intervals:
//  - R12 budget: ~4380 cyc/SIMD/tile = matrix 1020 + VALU ~900 + ds_read
//    ~400 + ~2000 stall (barrier/wait/dep-chain). R14's cross-block domains
//    regressed (doubled per-CU K/V traffic). So: halve the INTERVAL COUNT.
//  - 2-stage LDS of double-tiles (stage = K 16KB + V 16KB; 64 KB total).
//    Per interval: wait vmcnt(0) (loads issued one full pair-compute ago ->
//    free), barrier, DMA next pair (8 gld16/wave), compute tiles t0,t1 in
//    source order QK(t0),exp(t0),QK(t1),PV(t0),exp(t1),PV(t1):
//    QK(t1) indep of exp(t0); PV(t0) (matrix) indep of exp(t1) (VALU) ->
//    compiler interleaves across tiles WITHIN one basic block = the R7/R8
//    overlap goal with zero sync-structure risk (all data in one landed
//    stage, register deps only).
//  - Stage-overwrite proof unchanged from R12: stage written at interval p
//    was read at p-1; reads retired pre-barrier (compiler lgkmcnt before
//    pre-barrier MFMAs); all waves passed the barrier before the DMA.
//  - Per-tile math byte-identical to R12 (16 mfma_32x32x16, exp2, cvt_pk +
//    permlane32_swap repack, VALU lsum, same layouts / epilogue).
// Prep: R13 fused single-pass (unchanged). Fallback unchanged.

typedef __attribute__((ext_vector_type(8))) short short8_t;
typedef __attribute__((ext_vector_type(4))) short short4_t;
typedef __attribute__((ext_vector_type(4))) float float4_t;
typedef __attribute__((ext_vector_type(16))) float float16_t;

#define SEQ   2048
#define NBH   32
#define NKT   32

__device__ __forceinline__ unsigned f2bf2u(float a, float b) {
#if __has_builtin(__builtin_amdgcn_cvt_pk_bf16_f32)
  typedef __bf16 bf16x2_t __attribute__((ext_vector_type(2)));
  union { bf16x2_t v; unsigned u; } cv;
  cv.v = __builtin_amdgcn_cvt_pk_bf16_f32(a, b);
  return cv.u;
#else
  union { float f; unsigned u; } x, y;
  x.f = a; y.f = b;
  unsigned ra = x.u + 0x7fffu + ((x.u >> 16) & 1u);
  unsigned rb = y.u + 0x7fffu + ((y.u >> 16) & 1u);
  return (ra >> 16) | (rb & 0xffff0000u);
#endif
}

__device__ __forceinline__ short f2bf1(float a) {
  return (short)(f2bf2u(a, a) & 0xffffu);
}

__device__ __forceinline__ float fast_exp2(float x) {
#if __has_builtin(__builtin_amdgcn_exp2f)
  return __builtin_amdgcn_exp2f(x);
#else
  return exp2f(x);
#endif
}

__device__ __forceinline__ void gld16(const void* g, void* l) {
  __builtin_amdgcn_global_load_lds(
      (const __attribute__((address_space(1))) void*)g,
      (__attribute__((address_space(3))) void*)l, 16, 0, 0);
}

__device__ __forceinline__ float4_t mfma32(short8_t a, short8_t b, float4_t c) {
  return __builtin_amdgcn_mfma_f32_16x16x32_bf16(a, b, c, 0, 0, 0);
}

__device__ __forceinline__ float16_t mfma3232(short8_t a, short8_t b, float16_t c) {
  return __builtin_amdgcn_mfma_f32_32x32x16_bf16(a, b, c, 0, 0, 0);
}

// lane<32/lane>=32 half exchange: a' = [a_lo|b_lo], b' = [a_hi|b_hi]
__device__ __forceinline__ void plswap(unsigned& a, unsigned& b, int hi) {
#if __has_builtin(__builtin_amdgcn_permlane32_swap)
  typedef __attribute__((ext_vector_type(2))) unsigned uint2_t;
  uint2_t r = __builtin_amdgcn_permlane32_swap(a, b, false, false);
  a = r[0]; b = r[1];
#else
  const unsigned sa = (unsigned)__shfl_xor((int)a, 32);
  const unsigned sb = (unsigned)__shfl_xor((int)b, 32);
  const unsigned an = hi ? sb : a;
  const unsigned bn = hi ? b : sa;
  a = an; b = bn;
#endif
}

// ---------------- fused pre-pass (R13): one block per (bh,kt) ----------
// K -> Kt2[bh][kt][ch(8)][lr(64)][8]: out[ch*512+lr*8+j] = K[d=ch*8+j][k=lr]
// V -> Vt3[bh][kt][kc(8)][d(64)][8]:  out[(kc*64+d)*8+j] = V[d][k=kc*8+j]
#define PST 68
__global__ __launch_bounds__(256, 8)
void eia_prep_kernel(const float* __restrict__ kg, const float* __restrict__ vg,
                     unsigned short* __restrict__ Kt2, unsigned short* __restrict__ Vt2) {
  __shared__ __align__(16) short T[64 * PST];
  const int bh = blockIdx.x >> 5;
  const int kt = blockIdx.x & 31;
  const int t  = threadIdx.x;

  // ---- K phase: float4 loads along k, scatter bf16 to T[k][d] ----
  {
    const int dr = t >> 4;          // 0..15
    const int kq = (t & 15) * 4;    // 0,4,..,60
#pragma unroll
    for (int i = 0; i < 4; ++i) {
      const int d = i * 16 + dr;
      const float4_t f = *(const float4_t*)
          &kg[((size_t)bh * 64 + d) * SEQ + (size_t)(kt * 64 + kq)];
      T[(kq + 0) * PST + d] = f2bf1(f[0]);
      T[(kq + 1) * PST + d] = f2bf1(f[1]);
      T[(kq + 2) * PST + d] = f2bf1(f[2]);
      T[(kq + 3) * PST + d] = f2bf1(f[3]);
    }
  }
  __syncthreads();
  // K writeout (byte-identical to proven layout)
  {
    unsigned short* outt = Kt2 + (size_t)(bh * 32 + kt) * 4096;
#pragma unroll
    for (int rep = 0; rep < 2; ++rep) {
      const int id2 = rep * 256 + t;
      const int lr = id2 & 63, ch = id2 >> 6;
      union { short8_t v; short4_t h[2]; } o;
      o.h[0] = *(const short4_t*)&T[lr * PST + ch * 8];
      o.h[1] = *(const short4_t*)&T[lr * PST + ch * 8 + 4];
      *(short8_t*)&outt[ch * 512 + lr * 8] = o.v;
    }
  }
  __syncthreads();  // K reads of T done before V overwrites

  // ---- V phase: float4 loads along k into T[d][k] (proven pattern) ----
#pragma unroll
  for (int rep = 0; rep < 4; ++rep) {
    const int id2 = rep * 256 + t;
    const int d = id2 >> 4, l4 = (id2 & 15) * 4;
    const float4_t f = *(const float4_t*)
        &vg[((size_t)bh * 64 + d) * SEQ + (size_t)(kt * 64 + l4)];
    union { short4_t s; unsigned u[2]; } p;
    p.u[0] = f2bf2u(f[0], f[1]);
    p.u[1] = f2bf2u(f[2], f[3]);
    *(short4_t*)&T[d * PST + l4] = p.s;
  }
  __syncthreads();
  // Vt3 writeout (byte-identical to R12)
  {
    unsigned short* outt = Vt2 + (size_t)(bh * 32 + kt) * 4096;
#pragma unroll
    for (int rep = 0; rep < 2; ++rep) {
      const int c = rep * 256 + t;
      const int kc = c >> 6, d = c & 63;
      union { short8_t v; short4_t h[2]; } o;
      o.h[0] = *(const short4_t*)&T[d * PST + kc * 8];
      o.h[1] = *(const short4_t*)&T[d * PST + kc * 8 + 4];
      *(short8_t*)&outt[c * 8] = o.v;
    }
  }
}

// ---------------- main fused attention (R16: tile-pair intervals) ----------
// LDS (shorts): K stages [0,8192)|[8192,16384)   (stage = 2 tiles x 4096)
//               V stages [16384,24576)|[24576,32768)
// Q staging overlays [0, 8704) before the first DMA.  Total 64 KB.
__global__ __launch_bounds__(256, 2)
void eia_attn_kernel(const float* __restrict__ qg,
                     const unsigned short* __restrict__ Kt2,
                     const unsigned short* __restrict__ Vt2,
                     const int* __restrict__ klen,
                     float* __restrict__ outg) {
  __shared__ __align__(16) short SM[32768];

  const int tid   = threadIdx.x;
  const int bh    = blockIdx.x & 31;   // XCD = bh%8; 512 blocks = 2/CU
  const int qt    = blockIdx.x >> 5;
  const int q0    = qt * 128;
  const int qw    = tid >> 6;          // wave 0..3: q-tile qw*32
  const int lane  = tid & 63;
  const int l31   = lane & 31;
  const int hi    = lane >> 5;

  const float c = (1.4426950408889634f / (8.0f * 2.9957322735539909f)) *
                  logf((float)klen[bh >> 3]);
  const size_t qb = (size_t)bh * 64 * SEQ;

  // ---- Q stage: fp32 global -> SM[q][d] bf16 (stride 68), c folded ----
#pragma unroll
  for (int rep = 0; rep < 8; ++rep) {
    const int id = rep * 256 + tid;       // 0..2047
    const int d  = id >> 5;               // 0..63
    const int q4 = (id & 31) * 4;
    const float4_t f = *(const float4_t*)&qg[qb + (size_t)d * SEQ + (size_t)(q0 + q4)];
    SM[(q4 + 0) * 68 + d] = f2bf1(c * f[0]);
    SM[(q4 + 1) * 68 + d] = f2bf1(c * f[1]);
    SM[(q4 + 2) * 68 + d] = f2bf1(c * f[2]);
    SM[(q4 + 3) * 68 + d] = f2bf1(c * f[3]);
  }
  __syncthreads();

  // Q B-fragments (32x32x16 B-layout): B[d=s*16+hi*8+j][q=l31], s=0..3
  short8_t qfrag[4];
#pragma unroll
  for (int s = 0; s < 4; ++s) {
    const short* qp = &SM[(qw * 32 + l31) * 68 + s * 16 + hi * 8];
    const short4_t lo = *(const short4_t*)qp;
    const short4_t hh = *(const short4_t*)(qp + 4);
    qfrag[s] = short8_t{lo[0], lo[1], lo[2], lo[3], hh[0], hh[1], hh[2], hh[3]};
  }
  __syncthreads();  // Q reads done before DMA overwrites SM

  // ---- DMA setup: tile = 8 x 1KB instrs; wave qw covers instrs 2qw, 2qw+1 ----
  const char* ksrc = (const char*)Kt2 + (size_t)bh * NKT * 8192 + (2 * qw) * 1024 + lane * 16;
  const char* vsrc = (const char*)Vt2 + (size_t)bh * NKT * 8192 + (2 * qw) * 1024 + lane * 16;
  short* const kdst = &SM[(2 * qw) * 512];            // + stage*8192 + sub*4096
  short* const vdst = &SM[16384 + (2 * qw) * 512];

  // per-lane invariant fragment offset (shorts): hi*512 + l31*8
  const int lofs = hi * 512 + l31 * 8;
  const short* const kfp = &SM[lofs];
  const short* const vfp = &SM[16384 + lofs];

  const float16_t z16 = {0.f,0.f,0.f,0.f,0.f,0.f,0.f,0.f,
                         0.f,0.f,0.f,0.f,0.f,0.f,0.f,0.f};
  float16_t oacc0 = z16, oacc1 = z16;   // dt = 0,1
  float ls = 0.f;

  union pfu { short8_t s8; unsigned u[4]; };

// S^T = K^T * Q from tile base KB: 2 kb-halves x 4 chained mfma_32x32x16
#define EIA_QK(KB, S0, S1)                                                    \
  do {                                                                        \
    _Pragma("unroll")                                                         \
    for (int s = 0; s < 4; ++s)                                               \
      S0 = mfma3232(*(const short8_t*)((KB) + s * 1024), qfrag[s], S0);       \
    _Pragma("unroll")                                                         \
    for (int s = 0; s < 4; ++s)                                               \
      S1 = mfma3232(*(const short8_t*)((KB) + 256 + s * 1024), qfrag[s], S1); \
  } while (0)

// exp + lsum + P repack (C->B via cvt_pk + permlane32_swap) into PF[4]
#define EIA_EXPRP(S0, S1, PF)                                                 \
  do {                                                                        \
    _Pragma("unroll")                                                         \
    for (int kb = 0; kb < 2; ++kb) {                                          \
      float e[16];                                                            \
      _Pragma("unroll")                                                       \
      for (int r = 0; r < 16; ++r)                                            \
        e[r] = fast_exp2(kb == 0 ? S0[r] : S1[r]);                            \
      ls += (((e[0] + e[1]) + (e[2] + e[3])) +                                \
             ((e[4] + e[5]) + (e[6] + e[7]))) +                               \
            (((e[8] + e[9]) + (e[10] + e[11])) +                              \
             ((e[12] + e[13]) + (e[14] + e[15])));                            \
      _Pragma("unroll")                                                       \
      for (int ksl = 0; ksl < 2; ++ksl) {                                     \
        const int b = ksl * 8;                                                \
        unsigned a02 = f2bf2u(e[b + 0], e[b + 1]);                            \
        unsigned b02 = f2bf2u(e[b + 4], e[b + 5]);                            \
        unsigned a13 = f2bf2u(e[b + 2], e[b + 3]);                            \
        unsigned b13 = f2bf2u(e[b + 6], e[b + 7]);                            \
        plswap(a02, b02, hi);                                                 \
        plswap(a13, b13, hi);                                                 \
        PF[kb * 2 + ksl].u[0] = a02;                                          \
        PF[kb * 2 + ksl].u[1] = a13;                                          \
        PF[kb * 2 + ksl].u[2] = b02;                                          \
        PF[kb * 2 + ksl].u[3] = b13;                                          \
      }                                                                       \
    }                                                                         \
  } while (0)

// O^T += V * P^T from tile base VB: 2 dt x 4 chained mfma_32x32x16
#define EIA_PV(VB, PF)                                                        \
  do {                                                                        \
    _Pragma("unroll")                                                         \
    for (int ks = 0; ks < 4; ++ks)                                            \
      oacc0 = mfma3232(*(const short8_t*)((VB) + ks * 1024), PF[ks].s8, oacc0);\
    _Pragma("unroll")                                                         \
    for (int ks = 0; ks < 4; ++ks)                                            \
      oacc1 = mfma3232(*(const short8_t*)((VB) + 256 + ks * 1024),            \
                       PF[ks].s8, oacc1);                                     \
  } while (0)

  // ---- prologue: DMA pair 0 (tiles 0,1) -> stage 0 ----
#pragma unroll
  for (int i = 0; i < 2; ++i) {
    const size_t gb = (size_t)i * 8192;
    const int so = i * 4096;
    gld16(ksrc + gb, kdst + so); gld16(ksrc + gb + 1024, kdst + so + 512);
    gld16(vsrc + gb, vdst + so); gld16(vsrc + gb + 1024, vdst + so + 512);
  }

  int sc = 0;                // stage of current pair
  size_t gsrc = 16384;       // byte offset of pair p+1

  for (int p = 0; p < NKT / 2; ++p) {
    // drain: pair p's 8 loads (issued one full pair-compute ago, except p=0).
    asm volatile("s_waitcnt vmcnt(0)" ::: "memory");
    asm volatile("s_barrier" ::: "memory");

    // DMA pair p+1 into the other stage (read last interval; reads retired
    // pre-barrier -- same proof as R12's 3-stage rotation).
    if (p < NKT / 2 - 1) {
      const int so = (sc ^ 1) * 8192;
#pragma unroll
      for (int i = 0; i < 2; ++i) {
        gld16(ksrc + gsrc + (size_t)i * 8192, kdst + so + i * 4096);
        gld16(ksrc + gsrc + (size_t)i * 8192 + 1024, kdst + so + i * 4096 + 512);
        gld16(vsrc + gsrc + (size_t)i * 8192, vdst + so + i * 4096);
        gld16(vsrc + gsrc + (size_t)i * 8192 + 1024, vdst + so + i * 4096 + 512);
      }
      gsrc += 16384;
    }
    const int koff = sc * 8192;
    sc ^= 1;
    const short* const kb0 = kfp + koff;
    const short* const vb0 = vfp + koff;
    const short* const kb1 = kb0 + 4096;
    const short* const vb1 = vb0 + 4096;

    // interleaved pair: QK(t1) indep of exp(t0); PV(t0) (matrix) overlaps
    // exp(t1) (VALU) -- compiler schedules within this basic block.
    float16_t s0a = z16, s1a = z16, s0b = z16, s1b = z16;
    pfu pf0[4], pf1[4];
    EIA_QK(kb0, s0a, s1a);
    EIA_EXPRP(s0a, s1a, pf0);
    EIA_QK(kb1, s0b, s1b);
    EIA_PV(vb0, pf0);
    EIA_EXPRP(s0b, s1b, pf1);
    EIA_PV(vb1, pf1);
  }
#undef EIA_QK
#undef EIA_EXPRP
#undef EIA_PV

  // ---- epilogue: lsum cross-half add, normalize (lane's q = l31), store ----
  const float lst = ls + __shfl_xor(ls, 32);
  const float inv = 1.0f / lst;
  const size_t ob = qb + (size_t)(q0 + qw * 32 + l31);
#pragma unroll
  for (int r = 0; r < 16; ++r) {
    const int drow = (r & 3) + 8 * (r >> 2) + 4 * hi;
    outg[ob + (size_t)(drow) * SEQ]      = oacc0[r] * inv;
    outg[ob + (size_t)(drow + 32) * SEQ] = oacc1[r] * inv;
  }
}

// ---------------- fallback (ws too small): R2-style, known-good ----------------
#define DPAD  72
#define PPAD  68
__global__ __launch_bounds__(256, 5)
void eia_attn_fb(const float* __restrict__ qg, const float* __restrict__ kg,
                 const float* __restrict__ vg, const int* __restrict__ klen,
                 float* __restrict__ outg) {
  __shared__ __align__(16) short QPs[64 * DPAD];
  __shared__ __align__(16) short Ksf[64 * DPAD];
  __shared__ __align__(16) short Vsf[64 * DPAD];

  const int tid  = threadIdx.x;
  const int bh   = blockIdx.x & 31;
  const int qt   = blockIdx.x >> 5;
  const int q0   = qt * 64;
  const int w    = tid >> 6;
  const int lane = tid & 63;
  const int quad = lane >> 4;
  const int l16  = lane & 15;

  const size_t base = (size_t)bh * 64 * SEQ;
  const float c = (1.4426950408889634f / (8.0f * 2.9957322735539909f)) *
                  logf((float)klen[bh >> 3]);

#pragma unroll
  for (int it = 0; it < 2; ++it) {
    const int e = it * 4 + w;
    float f[8];
#pragma unroll
    for (int j = 0; j < 8; ++j)
      f[j] = c * qg[base + (size_t)(e * 8 + j) * SEQ + (size_t)(q0 + lane)];
    union { short8_t s8; unsigned u[4]; } t;
#pragma unroll
    for (int j = 0; j < 4; ++j) t.u[j] = f2bf2u(f[2 * j], f[2 * j + 1]);
    *(short8_t*)&QPs[lane * DPAD + e * 8] = t.s8;
  }
  __syncthreads();

  short8_t qfrag[2];
#pragma unroll
  for (int s = 0; s < 2; ++s)
    qfrag[s] = *(const short8_t*)&QPs[(w * 16 + l16) * DPAD + s * 32 + quad * 8];

  float4_t oacc[4];
#pragma unroll
  for (int t = 0; t < 4; ++t) { oacc[t][0] = 0.f; oacc[t][1] = 0.f; oacc[t][2] = 0.f; oacc[t][3] = 0.f; }
  float lsumv[4] = {0.f, 0.f, 0.f, 0.f};
  const int pbase = w * (16 * DPAD);

  for (int kt = 0; kt < NKT; ++kt) {
    const int k0 = kt * 64;
#pragma unroll
    for (int it = 0; it < 2; ++it) {
      float f[8];
#pragma unroll
      for (int j = 0; j < 8; ++j)
        f[j] = kg[base + (size_t)((it * 4 + w) * 8 + j) * SEQ + (size_t)(k0 + lane)];
      union { short8_t s8; unsigned u[4]; } t;
#pragma unroll
      for (int j = 0; j < 4; ++j) t.u[j] = f2bf2u(f[2 * j], f[2 * j + 1]);
      *(short8_t*)&Ksf[lane * DPAD + (it * 4 + w) * 8] = t.s8;
    }
#pragma unroll
    for (int it = 0; it < 4; ++it) {
      const int d = it * 16 + (w << 2) + (lane >> 4);
      const float4_t vv = *(const float4_t*)&vg[base + (size_t)d * SEQ + (size_t)(k0 + ((lane & 15) << 2))];
      union { short4_t s4; unsigned u[2]; } t;
      t.u[0] = f2bf2u(vv[0], vv[1]);
      t.u[1] = f2bf2u(vv[2], vv[3]);
      *(short4_t*)&Vsf[d * DPAD + ((lane & 15) << 2)] = t.s4;
    }
    __syncthreads();

    float4_t sacc[4];
#pragma unroll
    for (int t = 0; t < 4; ++t) { sacc[t][0] = 0.f; sacc[t][1] = 0.f; sacc[t][2] = 0.f; sacc[t][3] = 0.f; }
#pragma unroll
    for (int t = 0; t < 4; ++t)
#pragma unroll
      for (int s = 0; s < 2; ++s) {
        const short8_t bf = *(const short8_t*)&Ksf[(t * 16 + l16) * DPAD + s * 32 + quad * 8];
        sacc[t] = mfma32(qfrag[s], bf, sacc[t]);
      }

#pragma unroll
    for (int r = 0; r < 4; ++r) {
      const float p0 = fast_exp2(sacc[0][r]);
      const float p1 = fast_exp2(sacc[1][r]);
      const float p2 = fast_exp2(sacc[2][r]);
      const float p3 = fast_exp2(sacc[3][r]);
      lsumv[r] += (p0 + p1) + (p2 + p3);
      const int prow = pbase + (quad * 4 + r) * PPAD + l16;
      QPs[prow +  0] = f2bf1(p0);
      QPs[prow + 16] = f2bf1(p1);
      QPs[prow + 32] = f2bf1(p2);
      QPs[prow + 48] = f2bf1(p3);
    }

#pragma unroll
    for (int s = 0; s < 2; ++s) {
      const short* pr = &QPs[pbase + l16 * PPAD + s * 32 + quad * 8];
      const short4_t plo = *(const short4_t*)pr;
      const short4_t phi = *(const short4_t*)(pr + 4);
      const short8_t pfv = {plo[0], plo[1], plo[2], plo[3], phi[0], phi[1], phi[2], phi[3]};
#pragma unroll
      for (int t = 0; t < 4; ++t) {
        const short8_t vf = *(const short8_t*)&Vsf[(t * 16 + l16) * DPAD + s * 32 + quad * 8];
        oacc[t] = mfma32(pfv, vf, oacc[t]);
      }
    }
    __syncthreads();
  }

  float inv[4];
#pragma unroll
  for (int r = 0; r < 4; ++r) {
    float v = lsumv[r];
    v += __shfl_xor(v, 1);
    v += __shfl_xor(v, 2);
    v += __shfl_xor(v, 4);
    v += __shfl_xor(v, 8);
    inv[r] = 1.0f / v;
  }
#pragma unroll
  for (int t = 0; t < 4; ++t)
#pragma unroll
    for (int r = 0; r < 4; ++r)
      outg[base + (size_t)(t * 16 + l16) * SEQ +
           (size_t)(q0 + w * 16 + quad * 4 + r)] = oacc[t][r] * inv[r];
}

extern "C" void kernel_launch(void* const* d_in, const int* in_sizes, int n_in,
                              void* d_out, int out_size, void* d_ws, size_t ws_size,
                              hipStream_t stream) {
  const float* q  = (const float*)d_in[0];
  const float* k  = (const float*)d_in[1];
  const float* v  = (const float*)d_in[2];
  const int*   kl = (const int*)d_in[3];
  float* out = (float*)d_out;

  const size_t TEN  = (size_t)NBH * SEQ * 64;
  const size_t need = 2 * TEN * sizeof(unsigned short);  // 16.8 MB

  if (ws_size >= need) {
    unsigned short* Kt2 = (unsigned short*)d_ws;
    unsigned short* Vt2 = Kt2 + TEN;
    eia_prep_kernel<<<1024, 256, 0, stream>>>(k, v, Kt2, Vt2);
    eia_attn_kernel<<<512, 256, 0, stream>>>(q, Kt2, Vt2, kl, out);
  } else {
    eia_attn_fb<<<1024, 256, 0, stream>>>(q, k, v, kl, out);
  }
}

// Round 11
// 137.786 us; speedup vs baseline: 1.0584x; 1.0167x over previous
//
#include <hip/hip_runtime.h>
#include <hip/hip_bf16.h>
#include <math.h>

// EntropyInvarianceAttention: out = softmax(c * Q^T K) V^T per (b,h),
// c = ln(k_length[b]) / (8*ln(20)); q,k,v are (B, 512, 2048) fp32, l contiguous.
//
// R17 = R12 compute (32x32x16 MFMA path, 58.4us best) at 4 waves/SIMD:
//  - 10-round synthesis: every variant ran 2 waves/SIMD (Occupancy ~16%)
//    except R10 (4 waves/SIMD, the only structural win, +6%). ~35% of
//    cycles neither MFMA nor VALU issues -> latency unhidden at 2 waves.
//  - 512-thr blocks: 8 waves = 4 q-subtiles (qw, 32q) x 2 k-halves (h).
//    Grid 512 -> 2 blocks/CU x 8 waves = 16/CU = 4/SIMD.
//    Per wave per tile: 4 QK mfma (S-tile kb=h), 16 exp, 2 repacks,
//    4 PV mfma (ks = 2h..2h+1). Per-CU totals identical to R12.
//  - Sync skeleton = R10-proven: 3-stage {K 8KB|V 8KB} LDS (48KB), tile =
//    16 gld16 over 8 waves = 2/wave, prologue vmcnt(0) drain, steady
//    vmcnt(2) (retires tile kt, leaves kt+1 in flight), raw barrier,
//    DMA(kt+2). Stage-overwrite proof as R10/R12.
//  - Epilogue: k-half partials (oacc 32f + ls) combined via LDS (34.8KB
//    over retired stages; R10-proven pattern), h=0 normalizes + stores.
//  - __launch_bounds__(512,4) caps VGPR at 128 (est ~105) for 4 waves/EU.
// Prep: R13 fused single-pass (unchanged). Fallback unchanged.

typedef __attribute__((ext_vector_type(8))) short short8_t;
typedef __attribute__((ext_vector_type(4))) short short4_t;
typedef __attribute__((ext_vector_type(4))) float float4_t;
typedef __attribute__((ext_vector_type(16))) float float16_t;

#define SEQ   2048
#define NBH   32
#define NKT   32

__device__ __forceinline__ unsigned f2bf2u(float a, float b) {
#if __has_builtin(__builtin_amdgcn_cvt_pk_bf16_f32)
  typedef __bf16 bf16x2_t __attribute__((ext_vector_type(2)));
  union { bf16x2_t v; unsigned u; } cv;
  cv.v = __builtin_amdgcn_cvt_pk_bf16_f32(a, b);
  return cv.u;
#else
  union { float f; unsigned u; } x, y;
  x.f = a; y.f = b;
  unsigned ra = x.u + 0x7fffu + ((x.u >> 16) & 1u);
  unsigned rb = y.u + 0x7fffu + ((y.u >> 16) & 1u);
  return (ra >> 16) | (rb & 0xffff0000u);
#endif
}

__device__ __forceinline__ short f2bf1(float a) {
  return (short)(f2bf2u(a, a) & 0xffffu);
}

__device__ __forceinline__ float fast_exp2(float x) {
#if __has_builtin(__builtin_amdgcn_exp2f)
  return __builtin_amdgcn_exp2f(x);
#else
  return exp2f(x);
#endif
}

__device__ __forceinline__ void gld16(const void* g, void* l) {
  __builtin_amdgcn_global_load_lds(
      (const __attribute__((address_space(1))) void*)g,
      (__attribute__((address_space(3))) void*)l, 16, 0, 0);
}

__device__ __forceinline__ float4_t mfma32(short8_t a, short8_t b, float4_t c) {
  return __builtin_amdgcn_mfma_f32_16x16x32_bf16(a, b, c, 0, 0, 0);
}

__device__ __forceinline__ float16_t mfma3232(short8_t a, short8_t b, float16_t c) {
  return __builtin_amdgcn_mfma_f32_32x32x16_bf16(a, b, c, 0, 0, 0);
}

// lane<32/lane>=32 half exchange: a' = [a_lo|b_lo], b' = [a_hi|b_hi]
__device__ __forceinline__ void plswap(unsigned& a, unsigned& b, int hi) {
#if __has_builtin(__builtin_amdgcn_permlane32_swap)
  typedef __attribute__((ext_vector_type(2))) unsigned uint2_t;
  uint2_t r = __builtin_amdgcn_permlane32_swap(a, b, false, false);
  a = r[0]; b = r[1];
#else
  const unsigned sa = (unsigned)__shfl_xor((int)a, 32);
  const unsigned sb = (unsigned)__shfl_xor((int)b, 32);
  const unsigned an = hi ? sb : a;
  const unsigned bn = hi ? b : sa;
  a = an; b = bn;
#endif
}

// ---------------- fused pre-pass (R13): one block per (bh,kt) ----------
// K -> Kt2[bh][kt][ch(8)][lr(64)][8]: out[ch*512+lr*8+j] = K[d=ch*8+j][k=lr]
// V -> Vt3[bh][kt][kc(8)][d(64)][8]:  out[(kc*64+d)*8+j] = V[d][k=kc*8+j]
#define PST 68
__global__ __launch_bounds__(256, 8)
void eia_prep_kernel(const float* __restrict__ kg, const float* __restrict__ vg,
                     unsigned short* __restrict__ Kt2, unsigned short* __restrict__ Vt2) {
  __shared__ __align__(16) short T[64 * PST];
  const int bh = blockIdx.x >> 5;
  const int kt = blockIdx.x & 31;
  const int t  = threadIdx.x;

  // ---- K phase: float4 loads along k, scatter bf16 to T[k][d] ----
  {
    const int dr = t >> 4;          // 0..15
    const int kq = (t & 15) * 4;    // 0,4,..,60
#pragma unroll
    for (int i = 0; i < 4; ++i) {
      const int d = i * 16 + dr;
      const float4_t f = *(const float4_t*)
          &kg[((size_t)bh * 64 + d) * SEQ + (size_t)(kt * 64 + kq)];
      T[(kq + 0) * PST + d] = f2bf1(f[0]);
      T[(kq + 1) * PST + d] = f2bf1(f[1]);
      T[(kq + 2) * PST + d] = f2bf1(f[2]);
      T[(kq + 3) * PST + d] = f2bf1(f[3]);
    }
  }
  __syncthreads();
  // K writeout (byte-identical to proven layout)
  {
    unsigned short* outt = Kt2 + (size_t)(bh * 32 + kt) * 4096;
#pragma unroll
    for (int rep = 0; rep < 2; ++rep) {
      const int id2 = rep * 256 + t;
      const int lr = id2 & 63, ch = id2 >> 6;
      union { short8_t v; short4_t h[2]; } o;
      o.h[0] = *(const short4_t*)&T[lr * PST + ch * 8];
      o.h[1] = *(const short4_t*)&T[lr * PST + ch * 8 + 4];
      *(short8_t*)&outt[ch * 512 + lr * 8] = o.v;
    }
  }
  __syncthreads();  // K reads of T done before V overwrites

  // ---- V phase: float4 loads along k into T[d][k] (proven pattern) ----
#pragma unroll
  for (int rep = 0; rep < 4; ++rep) {
    const int id2 = rep * 256 + t;
    const int d = id2 >> 4, l4 = (id2 & 15) * 4;
    const float4_t f = *(const float4_t*)
        &vg[((size_t)bh * 64 + d) * SEQ + (size_t)(kt * 64 + l4)];
    union { short4_t s; unsigned u[2]; } p;
    p.u[0] = f2bf2u(f[0], f[1]);
    p.u[1] = f2bf2u(f[2], f[3]);
    *(short4_t*)&T[d * PST + l4] = p.s;
  }
  __syncthreads();
  // Vt3 writeout (byte-identical to R12)
  {
    unsigned short* outt = Vt2 + (size_t)(bh * 32 + kt) * 4096;
#pragma unroll
    for (int rep = 0; rep < 2; ++rep) {
      const int c = rep * 256 + t;
      const int kc = c >> 6, d = c & 63;
      union { short8_t v; short4_t h[2]; } o;
      o.h[0] = *(const short4_t*)&T[d * PST + kc * 8];
      o.h[1] = *(const short4_t*)&T[d * PST + kc * 8 + 4];
      *(short8_t*)&outt[c * 8] = o.v;
    }
  }
}

// ---------------- main fused attention (R17: 8 waves, k-half split) --------
// LDS (shorts): K stages [0,4096)|[4096,8192)|[8192,12288)
//               V stages [12288,16384)|[16384,20480)|[20480,24576)
// Q staging overlays [0, 8704); epilogue floats [0, 34816 B) after the loop.
__global__ __launch_bounds__(512, 4)
void eia_attn_kernel(const float* __restrict__ qg,
                     const unsigned short* __restrict__ Kt2,
                     const unsigned short* __restrict__ Vt2,
                     const int* __restrict__ klen,
                     float* __restrict__ outg) {
  __shared__ __align__(16) short SM[24576];

  const int tid   = threadIdx.x;
  const int bh    = blockIdx.x & 31;   // XCD = bh%8; 512 blocks = 2/CU
  const int qt    = blockIdx.x >> 5;
  const int q0    = qt * 128;
  const int wv    = tid >> 6;          // wave 0..7
  const int qw    = wv & 3;            // q-subtile (32 q)
  const int h     = wv >> 2;           // k-half: S-tile kb=h, ks=2h..2h+1
  const int lane  = tid & 63;
  const int l31   = lane & 31;
  const int hi    = lane >> 5;

  const float c = (1.4426950408889634f / (8.0f * 2.9957322735539909f)) *
                  logf((float)klen[bh >> 3]);
  const size_t qb = (size_t)bh * 64 * SEQ;

  // ---- Q stage: fp32 global -> SM[q][d] bf16 (stride 68), c folded ----
#pragma unroll
  for (int rep = 0; rep < 4; ++rep) {
    const int id = rep * 512 + tid;       // 0..2047
    const int d  = id >> 5;               // 0..63
    const int q4 = (id & 31) * 4;
    const float4_t f = *(const float4_t*)&qg[qb + (size_t)d * SEQ + (size_t)(q0 + q4)];
    SM[(q4 + 0) * 68 + d] = f2bf1(c * f[0]);
    SM[(q4 + 1) * 68 + d] = f2bf1(c * f[1]);
    SM[(q4 + 2) * 68 + d] = f2bf1(c * f[2]);
    SM[(q4 + 3) * 68 + d] = f2bf1(c * f[3]);
  }
  __syncthreads();

  // Q B-fragments (32x32x16 B-layout): B[d=s*16+hi*8+j][q=l31], s=0..3
  short8_t qfrag[4];
#pragma unroll
  for (int s = 0; s < 4; ++s) {
    const short* qp = &SM[(qw * 32 + l31) * 68 + s * 16 + hi * 8];
    const short4_t lo = *(const short4_t*)qp;
    const short4_t hh = *(const short4_t*)(qp + 4);
    qfrag[s] = short8_t{lo[0], lo[1], lo[2], lo[3], hh[0], hh[1], hh[2], hh[3]};
  }
  __syncthreads();  // Q reads done before DMA overwrites SM

  // ---- DMA setup: tile = 16 x 1KB instrs (8 K + 8 V) over 8 waves ----
  const char* ksrc = (const char*)Kt2 + (size_t)bh * NKT * 8192 + wv * 1024 + lane * 16;
  const char* vsrc = (const char*)Vt2 + (size_t)bh * NKT * 8192 + wv * 1024 + lane * 16;
  short* const kdst = &SM[wv * 512];            // + stage*4096 (HW adds lane*16B)
  short* const vdst = &SM[12288 + wv * 512];

  // per-lane invariant fragment offsets (shorts)
  const int lofs = hi * 512 + l31 * 8;
  const short* const kfp = &SM[lofs + h * 256];   // + koff + s*1024
  const short* const vfp = &SM[12288 + lofs];     // + koff + ks*1024 + dt*256

  const float16_t z16 = {0.f,0.f,0.f,0.f,0.f,0.f,0.f,0.f,
                         0.f,0.f,0.f,0.f,0.f,0.f,0.f,0.f};
  float16_t oacc0 = z16, oacc1 = z16;   // dt = 0,1 (k-half partials)
  float ls = 0.f;

  // ---- prologue: DMA tiles 0,1 -> stages 0,1 (2 loads/wave/tile) ----
  gld16(ksrc, kdst);               gld16(vsrc, vdst);
  gld16(ksrc + 8192, kdst + 4096); gld16(vsrc + 8192, vdst + 4096);
  // One-time full drain: no issue-order assumption on prologue loads.
  asm volatile("s_waitcnt vmcnt(0)" ::: "memory");

  int  sc = 0;              // stage (shorts offset/4096) of current tile
  int  sn = 2;              // stage of tile kt+2
  size_t gsrc = 2 * 8192;   // byte offset of tile kt+2

  for (int kt = 0; kt < NKT; ++kt) {
    // wait: current tile's 2 loads done; NEXT tile's 2 stay in flight.
    if (kt < NKT - 1) asm volatile("s_waitcnt vmcnt(2)" ::: "memory");
    else              asm volatile("s_waitcnt vmcnt(0)" ::: "memory");
    asm volatile("s_barrier" ::: "memory");

    // issue DMA for tile kt+2 into stage sn
    if (kt < NKT - 2) {
      const int so = sn * 4096;
      gld16(ksrc + gsrc, kdst + so);
      gld16(vsrc + gsrc, vdst + so);
      gsrc += 8192;
      sn = (sn == 2) ? 0 : sn + 1;
    }
    const int koff = sc * 4096;
    sc = (sc == 2) ? 0 : sc + 1;
    const short* const kb_ = kfp + koff;
    const short* const vb_ = vfp + koff;

    // ---- S^T = K^T * Q (this wave's kb-half): 4 chained mfma_32x32x16 ----
    float16_t s0 = z16;
#pragma unroll
    for (int s = 0; s < 4; ++s)
      s0 = mfma3232(*(const short8_t*)(kb_ + s * 1024), qfrag[s], s0);

    // ---- exp + lsum + P repack (C->B via cvt_pk + permlane32_swap) ----
    float e[16];
#pragma unroll
    for (int r = 0; r < 16; ++r) e[r] = fast_exp2(s0[r]);
    ls += (((e[0] + e[1]) + (e[2] + e[3])) + ((e[4] + e[5]) + (e[6] + e[7]))) +
          (((e[8] + e[9]) + (e[10] + e[11])) + ((e[12] + e[13]) + (e[14] + e[15])));
    union pfu { short8_t s8; unsigned u[4]; };
    pfu pf[2];
#pragma unroll
    for (int ksl = 0; ksl < 2; ++ksl) {
      const int b = ksl * 8;
      unsigned a02 = f2bf2u(e[b + 0], e[b + 1]);
      unsigned b02 = f2bf2u(e[b + 4], e[b + 5]);
      unsigned a13 = f2bf2u(e[b + 2], e[b + 3]);
      unsigned b13 = f2bf2u(e[b + 6], e[b + 7]);
      plswap(a02, b02, hi);
      plswap(a13, b13, hi);
      pf[ksl].u[0] = a02;
      pf[ksl].u[1] = a13;
      pf[ksl].u[2] = b02;
      pf[ksl].u[3] = b13;
    }

    // ---- O^T += V * P^T (ks = 2h+ksl): 2 dt x 2 chained mfma_32x32x16 ----
#pragma unroll
    for (int ksl = 0; ksl < 2; ++ksl)
      oacc0 = mfma3232(*(const short8_t*)(vb_ + (h * 2 + ksl) * 1024),
                       pf[ksl].s8, oacc0);
#pragma unroll
    for (int ksl = 0; ksl < 2; ++ksl)
      oacc1 = mfma3232(*(const short8_t*)(vb_ + 256 + (h * 2 + ksl) * 1024),
                       pf[ksl].s8, oacc1);
  }

  // ---- epilogue: combine k-halves via LDS, normalize (lane's q=l31), store ----
  __syncthreads();   // all waves done reading K/V stages
  union o16 { float16_t v; float4_t q[4]; };
  float* const FA = (float*)SM;
  float* const fb = FA + (size_t)(qw * 64 + lane) * 34;   // 34 f x 256 = 34816 B
  if (h == 1) {
    o16 a; a.v = oacc0;
    o16 b2; b2.v = oacc1;
#pragma unroll
    for (int i = 0; i < 4; ++i) *(float4_t*)(fb + i * 4)      = a.q[i];
#pragma unroll
    for (int i = 0; i < 4; ++i) *(float4_t*)(fb + 16 + i * 4) = b2.q[i];
    fb[32] = ls;
  }
  __syncthreads();
  if (h == 0) {
    o16 a; a.v = oacc0;
    o16 b2; b2.v = oacc1;
#pragma unroll
    for (int i = 0; i < 4; ++i) {
      const float4_t p0 = *(const float4_t*)(fb + i * 4);
      const float4_t p1 = *(const float4_t*)(fb + 16 + i * 4);
      a.q[i][0] += p0[0]; a.q[i][1] += p0[1]; a.q[i][2] += p0[2]; a.q[i][3] += p0[3];
      b2.q[i][0] += p1[0]; b2.q[i][1] += p1[1]; b2.q[i][2] += p1[2]; b2.q[i][3] += p1[3];
    }
    const float lsc = ls + fb[32];
    const float lst = lsc + __shfl_xor(lsc, 32);
    const float inv = 1.0f / lst;
    const size_t ob = qb + (size_t)(q0 + qw * 32 + l31);
#pragma unroll
    for (int r = 0; r < 16; ++r) {
      const int drow = (r & 3) + 8 * (r >> 2) + 4 * hi;
      outg[ob + (size_t)(drow) * SEQ]      = a.v[r] * inv;
      outg[ob + (size_t)(drow + 32) * SEQ] = b2.v[r] * inv;
    }
  }
}

// ---------------- fallback (ws too small): R2-style, known-good ----------------
#define DPAD  72
#define PPAD  68
__global__ __launch_bounds__(256, 5)
void eia_attn_fb(const float* __restrict__ qg, const float* __restrict__ kg,
                 const float* __restrict__ vg, const int* __restrict__ klen,
                 float* __restrict__ outg) {
  __shared__ __align__(16) short QPs[64 * DPAD];
  __shared__ __align__(16) short Ksf[64 * DPAD];
  __shared__ __align__(16) short Vsf[64 * DPAD];

  const int tid  = threadIdx.x;
  const int bh   = blockIdx.x & 31;
  const int qt   = blockIdx.x >> 5;
  const int q0   = qt * 64;
  const int w    = tid >> 6;
  const int lane = tid & 63;
  const int quad = lane >> 4;
  const int l16  = lane & 15;

  const size_t base = (size_t)bh * 64 * SEQ;
  const float c = (1.4426950408889634f / (8.0f * 2.9957322735539909f)) *
                  logf((float)klen[bh >> 3]);

#pragma unroll
  for (int it = 0; it < 2; ++it) {
    const int e = it * 4 + w;
    float f[8];
#pragma unroll
    for (int j = 0; j < 8; ++j)
      f[j] = c * qg[base + (size_t)(e * 8 + j) * SEQ + (size_t)(q0 + lane)];
    union { short8_t s8; unsigned u[4]; } t;
#pragma unroll
    for (int j = 0; j < 4; ++j) t.u[j] = f2bf2u(f[2 * j], f[2 * j + 1]);
    *(short8_t*)&QPs[lane * DPAD + e * 8] = t.s8;
  }
  __syncthreads();

  short8_t qfrag[2];
#pragma unroll
  for (int s = 0; s < 2; ++s)
    qfrag[s] = *(const short8_t*)&QPs[(w * 16 + l16) * DPAD + s * 32 + quad * 8];

  float4_t oacc[4];
#pragma unroll
  for (int t = 0; t < 4; ++t) { oacc[t][0] = 0.f; oacc[t][1] = 0.f; oacc[t][2] = 0.f; oacc[t][3] = 0.f; }
  float lsumv[4] = {0.f, 0.f, 0.f, 0.f};
  const int pbase = w * (16 * DPAD);

  for (int kt = 0; kt < NKT; ++kt) {
    const int k0 = kt * 64;
#pragma unroll
    for (int it = 0; it < 2; ++it) {
      float f[8];
#pragma unroll
      for (int j = 0; j < 8; ++j)
        f[j] = kg[base + (size_t)((it * 4 + w) * 8 + j) * SEQ + (size_t)(k0 + lane)];
      union { short8_t s8; unsigned u[4]; } t;
#pragma unroll
      for (int j = 0; j < 4; ++j) t.u[j] = f2bf2u(f[2 * j], f[2 * j + 1]);
      *(short8_t*)&Ksf[lane * DPAD + (it * 4 + w) * 8] = t.s8;
    }
#pragma unroll
    for (int it = 0; it < 4; ++it) {
      const int d = it * 16 + (w << 2) + (lane >> 4);
      const float4_t vv = *(const float4_t*)&vg[base + (size_t)d * SEQ + (size_t)(k0 + ((lane & 15) << 2))];
      union { short4_t s4; unsigned u[2]; } t;
      t.u[0] = f2bf2u(vv[0], vv[1]);
      t.u[1] = f2bf2u(vv[2], vv[3]);
      *(short4_t*)&Vsf[d * DPAD + ((lane & 15) << 2)] = t.s4;
    }
    __syncthreads();

    float4_t sacc[4];
#pragma unroll
    for (int t = 0; t < 4; ++t) { sacc[t][0] = 0.f; sacc[t][1] = 0.f; sacc[t][2] = 0.f; sacc[t][3] = 0.f; }
#pragma unroll
    for (int t = 0; t < 4; ++t)
#pragma unroll
      for (int s = 0; s < 2; ++s) {
        const short8_t bf = *(const short8_t*)&Ksf[(t * 16 + l16) * DPAD + s * 32 + quad * 8];
        sacc[t] = mfma32(qfrag[s], bf, sacc[t]);
      }

#pragma unroll
    for (int r = 0; r < 4; ++r) {
      const float p0 = fast_exp2(sacc[0][r]);
      const float p1 = fast_exp2(sacc[1][r]);
      const float p2 = fast_exp2(sacc[2][r]);
      const float p3 = fast_exp2(sacc[3][r]);
      lsumv[r] += (p0 + p1) + (p2 + p3);
      const int prow = pbase + (quad * 4 + r) * PPAD + l16;
      QPs[prow +  0] = f2bf1(p0);
      QPs[prow + 16] = f2bf1(p1);
      QPs[prow + 32] = f2bf1(p2);
      QPs[prow + 48] = f2bf1(p3);
    }

#pragma unroll
    for (int s = 0; s < 2; ++s) {
      const short* pr = &QPs[pbase + l16 * PPAD + s * 32 + quad * 8];
      const short4_t plo = *(const short4_t*)pr;
      const short4_t phi = *(const short4_t*)(pr + 4);
      const short8_t pfv = {plo[0], plo[1], plo[2], plo[3], phi[0], phi[1], phi[2], phi[3]};
#pragma unroll
      for (int t = 0; t < 4; ++t) {
        const short8_t vf = *(const short8_t*)&Vsf[(t * 16 + l16) * DPAD + s * 32 + quad * 8];
        oacc[t] = mfma32(pfv, vf, oacc[t]);
      }
    }
    __syncthreads();
  }

  float inv[4];
#pragma unroll
  for (int r = 0; r < 4; ++r) {
    float v = lsumv[r];
    v += __shfl_xor(v, 1);
    v += __shfl_xor(v, 2);
    v += __shfl_xor(v, 4);
    v += __shfl_xor(v, 8);
    inv[r] = 1.0f / v;
  }
#pragma unroll
  for (int t = 0; t < 4; ++t)
#pragma unroll
    for (int r = 0; r < 4; ++r)
      outg[base + (size_t)(t * 16 + l16) * SEQ +
           (size_t)(q0 + w * 16 + quad * 4 + r)] = oacc[t][r] * inv[r];
}

extern "C" void kernel_launch(void* const* d_in, const int* in_sizes, int n_in,
                              void* d_out, int out_size, void* d_ws, size_t ws_size,
                              hipStream_t stream) {
  const float* q  = (const float*)d_in[0];
  const float* k  = (const float*)d_in[1];
  const float* v  = (const float*)d_in[2];
  const int*   kl = (const int*)d_in[3];
  float* out = (float*)d_out;

  const size_t TEN  = (size_t)NBH * SEQ * 64;
  const size_t need = 2 * TEN * sizeof(unsigned short);  // 16.8 MB

  if (ws_size >= need) {
    unsigned short* Kt2 = (unsigned short*)d_ws;
    unsigned short* Vt2 = Kt2 + TEN;
    eia_prep_kernel<<<1024, 256, 0, stream>>>(k, v, Kt2, Vt2);
    eia_attn_kernel<<<512, 512, 0, stream>>>(q, Kt2, Vt2, kl, out);
  } else {
    eia_attn_fb<<<1024, 256, 0, stream>>>(q, k, v, kl, out);
  }
}

// Round 13
// 134.455 us; speedup vs baseline: 1.0846x; 1.0248x over previous
//
#include <hip/hip_runtime.h>
#include <hip/hip_bf16.h>
#include <math.h>

// EntropyInvarianceAttention: out = softmax(c * Q^T K) V^T per (b,h),
// c = ln(k_length[b]) / (8*ln(20)); q,k,v are (B, 512, 2048) fp32, l contiguous.
//
// R20 = R17 (last passing: 137.8us total / 58.4us attn; 512x512, 8 waves =
// 4 q-subtiles x 2 k-halves, 3-stage LDS, proven sync) + EXACTLY ONE delta:
//  - f2bf2u -> raw `v_cvt_pk_bf16_f32` inline asm (1 instr vs 7-instr
//    integer round/pack fallback; the builtin does not exist on gfx950).
//    This is the guide's T12/m201/m214 recipe, HW-refcheck'd there.
//  - R19 post-mortem: R19 bundled this with raw-asm v_exp_f32 and a
//    ones-MFMA lsum and failed (absmax 2.6). The exp asm is the prime
//    suspect: CDNA trans ops have an exposed-latency wait-state before a
//    consuming VALU op; raw asm hides the trans op from the compiler so it
//    cannot insert the required wait -> stale P values. The ORIGINAL
//    __has_builtin(__builtin_amdgcn_exp2f) guard already emitted a single
//    v_exp_f32 WITH compiler hazard handling, so exp was never the VALU
//    bloat -- cvt_pk's 7-instr fallback (8/tile + staging) was. exp2
//    REVERTED to the builtin; VALU lsum + epilogue byte-identical to R17.
// Prep (R13 fused) and fallback unchanged; they inherit the cheaper cvt.

typedef __attribute__((ext_vector_type(8))) short short8_t;
typedef __attribute__((ext_vector_type(4))) short short4_t;
typedef __attribute__((ext_vector_type(4))) float float4_t;
typedef __attribute__((ext_vector_type(16))) float float16_t;

#define SEQ   2048
#define NBH   32
#define NKT   32

// pack two f32 -> one u32 of 2 bf16 (lo = a, hi = b), single instruction.
// T12/m201/m214 recipe (HW-refcheck'd); no builtin exists on gfx950.
__device__ __forceinline__ unsigned f2bf2u(float a, float b) {
  unsigned r;
  asm("v_cvt_pk_bf16_f32 %0, %1, %2" : "=v"(r) : "v"(a), "v"(b));
  return r;
}

__device__ __forceinline__ short f2bf1(float a) {
  return (short)(f2bf2u(a, a) & 0xffffu);
}

// 2^x via the builtin: compiler knows the trans-op hazard rules (R19 lesson:
// raw asm v_exp_f32 -> missing wait states -> stale reads -> wrong output).
__device__ __forceinline__ float fast_exp2(float x) {
#if __has_builtin(__builtin_amdgcn_exp2f)
  return __builtin_amdgcn_exp2f(x);
#else
  return exp2f(x);
#endif
}

__device__ __forceinline__ void gld16(const void* g, void* l) {
  __builtin_amdgcn_global_load_lds(
      (const __attribute__((address_space(1))) void*)g,
      (__attribute__((address_space(3))) void*)l, 16, 0, 0);
}

__device__ __forceinline__ float4_t mfma32(short8_t a, short8_t b, float4_t c) {
  return __builtin_amdgcn_mfma_f32_16x16x32_bf16(a, b, c, 0, 0, 0);
}

__device__ __forceinline__ float16_t mfma3232(short8_t a, short8_t b, float16_t c) {
  return __builtin_amdgcn_mfma_f32_32x32x16_bf16(a, b, c, 0, 0, 0);
}

// lane<32/lane>=32 half exchange: a' = [a_lo|b_lo], b' = [a_hi|b_hi]
__device__ __forceinline__ void plswap(unsigned& a, unsigned& b, int hi) {
#if __has_builtin(__builtin_amdgcn_permlane32_swap)
  typedef __attribute__((ext_vector_type(2))) unsigned uint2_t;
  uint2_t r = __builtin_amdgcn_permlane32_swap(a, b, false, false);
  a = r[0]; b = r[1];
#else
  const unsigned sa = (unsigned)__shfl_xor((int)a, 32);
  const unsigned sb = (unsigned)__shfl_xor((int)b, 32);
  const unsigned an = hi ? sb : a;
  const unsigned bn = hi ? b : sa;
  a = an; b = bn;
#endif
}

// ---------------- fused pre-pass (R13): one block per (bh,kt) ----------
// K -> Kt2[bh][kt][ch(8)][lr(64)][8]: out[ch*512+lr*8+j] = K[d=ch*8+j][k=lr]
// V -> Vt3[bh][kt][kc(8)][d(64)][8]:  out[(kc*64+d)*8+j] = V[d][k=kc*8+j]
#define PST 68
__global__ __launch_bounds__(256, 8)
void eia_prep_kernel(const float* __restrict__ kg, const float* __restrict__ vg,
                     unsigned short* __restrict__ Kt2, unsigned short* __restrict__ Vt2) {
  __shared__ __align__(16) short T[64 * PST];
  const int bh = blockIdx.x >> 5;
  const int kt = blockIdx.x & 31;
  const int t  = threadIdx.x;

  // ---- K phase: float4 loads along k, scatter bf16 to T[k][d] ----
  {
    const int dr = t >> 4;          // 0..15
    const int kq = (t & 15) * 4;    // 0,4,..,60
#pragma unroll
    for (int i = 0; i < 4; ++i) {
      const int d = i * 16 + dr;
      const float4_t f = *(const float4_t*)
          &kg[((size_t)bh * 64 + d) * SEQ + (size_t)(kt * 64 + kq)];
      T[(kq + 0) * PST + d] = f2bf1(f[0]);
      T[(kq + 1) * PST + d] = f2bf1(f[1]);
      T[(kq + 2) * PST + d] = f2bf1(f[2]);
      T[(kq + 3) * PST + d] = f2bf1(f[3]);
    }
  }
  __syncthreads();
  // K writeout (byte-identical to proven layout)
  {
    unsigned short* outt = Kt2 + (size_t)(bh * 32 + kt) * 4096;
#pragma unroll
    for (int rep = 0; rep < 2; ++rep) {
      const int id2 = rep * 256 + t;
      const int lr = id2 & 63, ch = id2 >> 6;
      union { short8_t v; short4_t h[2]; } o;
      o.h[0] = *(const short4_t*)&T[lr * PST + ch * 8];
      o.h[1] = *(const short4_t*)&T[lr * PST + ch * 8 + 4];
      *(short8_t*)&outt[ch * 512 + lr * 8] = o.v;
    }
  }
  __syncthreads();  // K reads of T done before V overwrites

  // ---- V phase: float4 loads along k into T[d][k] (proven pattern) ----
#pragma unroll
  for (int rep = 0; rep < 4; ++rep) {
    const int id2 = rep * 256 + t;
    const int d = id2 >> 4, l4 = (id2 & 15) * 4;
    const float4_t f = *(const float4_t*)
        &vg[((size_t)bh * 64 + d) * SEQ + (size_t)(kt * 64 + l4)];
    union { short4_t s; unsigned u[2]; } p;
    p.u[0] = f2bf2u(f[0], f[1]);
    p.u[1] = f2bf2u(f[2], f[3]);
    *(short4_t*)&T[d * PST + l4] = p.s;
  }
  __syncthreads();
  // Vt3 writeout (byte-identical to R12)
  {
    unsigned short* outt = Vt2 + (size_t)(bh * 32 + kt) * 4096;
#pragma unroll
    for (int rep = 0; rep < 2; ++rep) {
      const int c = rep * 256 + t;
      const int kc = c >> 6, d = c & 63;
      union { short8_t v; short4_t h[2]; } o;
      o.h[0] = *(const short4_t*)&T[d * PST + kc * 8];
      o.h[1] = *(const short4_t*)&T[d * PST + kc * 8 + 4];
      *(short8_t*)&outt[c * 8] = o.v;
    }
  }
}

// ---------------- main fused attention (R20: R17 + 1-instr cvt_pk) --------
// LDS (shorts): K stages [0,4096)|[4096,8192)|[8192,12288)
//               V stages [12288,16384)|[16384,20480)|[20480,24576)
// Q staging overlays [0, 8704); epilogue floats [0, 34816 B) after the loop.
__global__ __launch_bounds__(512, 4)
void eia_attn_kernel(const float* __restrict__ qg,
                     const unsigned short* __restrict__ Kt2,
                     const unsigned short* __restrict__ Vt2,
                     const int* __restrict__ klen,
                     float* __restrict__ outg) {
  __shared__ __align__(16) short SM[24576];

  const int tid   = threadIdx.x;
  const int bh    = blockIdx.x & 31;   // XCD = bh%8; 512 blocks = 2/CU
  const int qt    = blockIdx.x >> 5;
  const int q0    = qt * 128;
  const int wv    = tid >> 6;          // wave 0..7
  const int qw    = wv & 3;            // q-subtile (32 q)
  const int h     = wv >> 2;           // k-half: S-tile kb=h, ks=2h..2h+1
  const int lane  = tid & 63;
  const int l31   = lane & 31;
  const int hi    = lane >> 5;

  const float c = (1.4426950408889634f / (8.0f * 2.9957322735539909f)) *
                  logf((float)klen[bh >> 3]);
  const size_t qb = (size_t)bh * 64 * SEQ;

  // ---- Q stage: fp32 global -> SM[q][d] bf16 (stride 68), c folded ----
#pragma unroll
  for (int rep = 0; rep < 4; ++rep) {
    const int id = rep * 512 + tid;       // 0..2047
    const int d  = id >> 5;               // 0..63
    const int q4 = (id & 31) * 4;
    const float4_t f = *(const float4_t*)&qg[qb + (size_t)d * SEQ + (size_t)(q0 + q4)];
    SM[(q4 + 0) * 68 + d] = f2bf1(c * f[0]);
    SM[(q4 + 1) * 68 + d] = f2bf1(c * f[1]);
    SM[(q4 + 2) * 68 + d] = f2bf1(c * f[2]);
    SM[(q4 + 3) * 68 + d] = f2bf1(c * f[3]);
  }
  __syncthreads();

  // Q B-fragments (32x32x16 B-layout): B[d=s*16+hi*8+j][q=l31], s=0..3
  short8_t qfrag[4];
#pragma unroll
  for (int s = 0; s < 4; ++s) {
    const short* qp = &SM[(qw * 32 + l31) * 68 + s * 16 + hi * 8];
    const short4_t lo = *(const short4_t*)qp;
    const short4_t hh = *(const short4_t*)(qp + 4);
    qfrag[s] = short8_t{lo[0], lo[1], lo[2], lo[3], hh[0], hh[1], hh[2], hh[3]};
  }
  __syncthreads();  // Q reads done before DMA overwrites SM

  // ---- DMA setup: tile = 16 x 1KB instrs (8 K + 8 V) over 8 waves ----
  const char* ksrc = (const char*)Kt2 + (size_t)bh * NKT * 8192 + wv * 1024 + lane * 16;
  const char* vsrc = (const char*)Vt2 + (size_t)bh * NKT * 8192 + wv * 1024 + lane * 16;
  short* const kdst = &SM[wv * 512];            // + stage*4096 (HW adds lane*16B)
  short* const vdst = &SM[12288 + wv * 512];

  // per-lane invariant fragment offsets (shorts)
  const int lofs = hi * 512 + l31 * 8;
  const short* const kfp = &SM[lofs + h * 256];   // + koff + s*1024
  const short* const vfp = &SM[12288 + lofs];     // + koff + ks*1024 + dt*256

  const float16_t z16 = {0.f,0.f,0.f,0.f,0.f,0.f,0.f,0.f,
                         0.f,0.f,0.f,0.f,0.f,0.f,0.f,0.f};
  float16_t oacc0 = z16, oacc1 = z16;   // dt = 0,1 (k-half partials)
  float ls = 0.f;

  // ---- prologue: DMA tiles 0,1 -> stages 0,1 (2 loads/wave/tile) ----
  gld16(ksrc, kdst);               gld16(vsrc, vdst);
  gld16(ksrc + 8192, kdst + 4096); gld16(vsrc + 8192, vdst + 4096);
  // One-time full drain: no issue-order assumption on prologue loads.
  asm volatile("s_waitcnt vmcnt(0)" ::: "memory");

  int  sc = 0;              // stage (shorts offset/4096) of current tile
  int  sn = 2;              // stage of tile kt+2
  size_t gsrc = 2 * 8192;   // byte offset of tile kt+2

  for (int kt = 0; kt < NKT; ++kt) {
    // wait: current tile's 2 loads done; NEXT tile's 2 stay in flight.
    if (kt < NKT - 1) asm volatile("s_waitcnt vmcnt(2)" ::: "memory");
    else              asm volatile("s_waitcnt vmcnt(0)" ::: "memory");
    asm volatile("s_barrier" ::: "memory");

    // issue DMA for tile kt+2 into stage sn
    if (kt < NKT - 2) {
      const int so = sn * 4096;
      gld16(ksrc + gsrc, kdst + so);
      gld16(vsrc + gsrc, vdst + so);
      gsrc += 8192;
      sn = (sn == 2) ? 0 : sn + 1;
    }
    const int koff = sc * 4096;
    sc = (sc == 2) ? 0 : sc + 1;
    const short* const kb_ = kfp + koff;
    const short* const vb_ = vfp + koff;

    // ---- S^T = K^T * Q (this wave's kb-half): 4 chained mfma_32x32x16 ----
    float16_t s0 = z16;
#pragma unroll
    for (int s = 0; s < 4; ++s)
      s0 = mfma3232(*(const short8_t*)(kb_ + s * 1024), qfrag[s], s0);

    // ---- exp + lsum + P repack (C->B via cvt_pk + permlane32_swap) ----
    float e[16];
#pragma unroll
    for (int r = 0; r < 16; ++r) e[r] = fast_exp2(s0[r]);
    ls += (((e[0] + e[1]) + (e[2] + e[3])) + ((e[4] + e[5]) + (e[6] + e[7]))) +
          (((e[8] + e[9]) + (e[10] + e[11])) + ((e[12] + e[13]) + (e[14] + e[15])));
    union pfu { short8_t s8; unsigned u[4]; };
    pfu pf[2];
#pragma unroll
    for (int ksl = 0; ksl < 2; ++ksl) {
      const int b = ksl * 8;
      unsigned a02 = f2bf2u(e[b + 0], e[b + 1]);
      unsigned b02 = f2bf2u(e[b + 4], e[b + 5]);
      unsigned a13 = f2bf2u(e[b + 2], e[b + 3]);
      unsigned b13 = f2bf2u(e[b + 6], e[b + 7]);
      plswap(a02, b02, hi);
      plswap(a13, b13, hi);
      pf[ksl].u[0] = a02;
      pf[ksl].u[1] = a13;
      pf[ksl].u[2] = b02;
      pf[ksl].u[3] = b13;
    }

    // ---- O^T += V * P^T (ks = 2h+ksl): 2 dt x 2 chained mfma_32x32x16 ----
#pragma unroll
    for (int ksl = 0; ksl < 2; ++ksl)
      oacc0 = mfma3232(*(const short8_t*)(vb_ + (h * 2 + ksl) * 1024),
                       pf[ksl].s8, oacc0);
#pragma unroll
    for (int ksl = 0; ksl < 2; ++ksl)
      oacc1 = mfma3232(*(const short8_t*)(vb_ + 256 + (h * 2 + ksl) * 1024),
                       pf[ksl].s8, oacc1);
  }

  // ---- epilogue: combine k-halves via LDS, normalize (lane's q=l31), store ----
  __syncthreads();   // all waves done reading K/V stages
  union o16 { float16_t v; float4_t q[4]; };
  float* const FA = (float*)SM;
  float* const fb = FA + (size_t)(qw * 64 + lane) * 34;   // 34 f x 256 = 34816 B
  if (h == 1) {
    o16 a; a.v = oacc0;
    o16 b2; b2.v = oacc1;
#pragma unroll
    for (int i = 0; i < 4; ++i) *(float4_t*)(fb + i * 4)      = a.q[i];
#pragma unroll
    for (int i = 0; i < 4; ++i) *(float4_t*)(fb + 16 + i * 4) = b2.q[i];
    fb[32] = ls;
  }
  __syncthreads();
  if (h == 0) {
    o16 a; a.v = oacc0;
    o16 b2; b2.v = oacc1;
#pragma unroll
    for (int i = 0; i < 4; ++i) {
      const float4_t p0 = *(const float4_t*)(fb + i * 4);
      const float4_t p1 = *(const float4_t*)(fb + 16 + i * 4);
      a.q[i][0] += p0[0]; a.q[i][1] += p0[1]; a.q[i][2] += p0[2]; a.q[i][3] += p0[3];
      b2.q[i][0] += p1[0]; b2.q[i][1] += p1[1]; b2.q[i][2] += p1[2]; b2.q[i][3] += p1[3];
    }
    const float lsc = ls + fb[32];
    const float lst = lsc + __shfl_xor(lsc, 32);
    const float inv = 1.0f / lst;
    const size_t ob = qb + (size_t)(q0 + qw * 32 + l31);
#pragma unroll
    for (int r = 0; r < 16; ++r) {
      const int drow = (r & 3) + 8 * (r >> 2) + 4 * hi;
      outg[ob + (size_t)(drow) * SEQ]      = a.v[r] * inv;
      outg[ob + (size_t)(drow + 32) * SEQ] = b2.v[r] * inv;
    }
  }
}

// ---------------- fallback (ws too small): R2-style, known-good ----------------
#define DPAD  72
#define PPAD  68
__global__ __launch_bounds__(256, 5)
void eia_attn_fb(const float* __restrict__ qg, const float* __restrict__ kg,
                 const float* __restrict__ vg, const int* __restrict__ klen,
                 float* __restrict__ outg) {
  __shared__ __align__(16) short QPs[64 * DPAD];
  __shared__ __align__(16) short Ksf[64 * DPAD];
  __shared__ __align__(16) short Vsf[64 * DPAD];

  const int tid  = threadIdx.x;
  const int bh   = blockIdx.x & 31;
  const int qt   = blockIdx.x >> 5;
  const int q0   = qt * 64;
  const int w    = tid >> 6;
  const int lane = tid & 63;
  const int quad = lane >> 4;
  const int l16  = lane & 15;

  const size_t base = (size_t)bh * 64 * SEQ;
  const float c = (1.4426950408889634f / (8.0f * 2.9957322735539909f)) *
                  logf((float)klen[bh >> 3]);

#pragma unroll
  for (int it = 0; it < 2; ++it) {
    const int e = it * 4 + w;
    float f[8];
#pragma unroll
    for (int j = 0; j < 8; ++j)
      f[j] = c * qg[base + (size_t)(e * 8 + j) * SEQ + (size_t)(q0 + lane)];
    union { short8_t s8; unsigned u[4]; } t;
#pragma unroll
    for (int j = 0; j < 4; ++j) t.u[j] = f2bf2u(f[2 * j], f[2 * j + 1]);
    *(short8_t*)&QPs[lane * DPAD + e * 8] = t.s8;
  }
  __syncthreads();

  short8_t qfrag[2];
#pragma unroll
  for (int s = 0; s < 2; ++s)
    qfrag[s] = *(const short8_t*)&QPs[(w * 16 + l16) * DPAD + s * 32 + quad * 8];

  float4_t oacc[4];
#pragma unroll
  for (int t = 0; t < 4; ++t) { oacc[t][0] = 0.f; oacc[t][1] = 0.f; oacc[t][2] = 0.f; oacc[t][3] = 0.f; }
  float lsumv[4] = {0.f, 0.f, 0.f, 0.f};
  const int pbase = w * (16 * DPAD);

  for (int kt = 0; kt < NKT; ++kt) {
    const int k0 = kt * 64;
#pragma unroll
    for (int it = 0; it < 2; ++it) {
      float f[8];
#pragma unroll
      for (int j = 0; j < 8; ++j)
        f[j] = kg[base + (size_t)((it * 4 + w) * 8 + j) * SEQ + (size_t)(k0 + lane)];
      union { short8_t s8; unsigned u[4]; } t;
#pragma unroll
      for (int j = 0; j < 4; ++j) t.u[j] = f2bf2u(f[2 * j], f[2 * j + 1]);
      *(short8_t*)&Ksf[lane * DPAD + (it * 4 + w) * 8] = t.s8;
    }
#pragma unroll
    for (int it = 0; it < 4; ++it) {
      const int d = it * 16 + (w << 2) + (lane >> 4);
      const float4_t vv = *(const float4_t*)&vg[base + (size_t)d * SEQ + (size_t)(k0 + ((lane & 15) << 2))];
      union { short4_t s4; unsigned u[2]; } t;
      t.u[0] = f2bf2u(vv[0], vv[1]);
      t.u[1] = f2bf2u(vv[2], vv[3]);
      *(short4_t*)&Vsf[d * DPAD + ((lane & 15) << 2)] = t.s4;
    }
    __syncthreads();

    float4_t sacc[4];
#pragma unroll
    for (int t = 0; t < 4; ++t) { sacc[t][0] = 0.f; sacc[t][1] = 0.f; sacc[t][2] = 0.f; sacc[t][3] = 0.f; }
#pragma unroll
    for (int t = 0; t < 4; ++t)
#pragma unroll
      for (int s = 0; s < 2; ++s) {
        const short8_t bf = *(const short8_t*)&Ksf[(t * 16 + l16) * DPAD + s * 32 + quad * 8];
        sacc[t] = mfma32(qfrag[s], bf, sacc[t]);
      }

#pragma unroll
    for (int r = 0; r < 4; ++r) {
      const float p0 = fast_exp2(sacc[0][r]);
      const float p1 = fast_exp2(sacc[1][r]);
      const float p2 = fast_exp2(sacc[2][r]);
      const float p3 = fast_exp2(sacc[3][r]);
      lsumv[r] += (p0 + p1) + (p2 + p3);
      const int prow = pbase + (quad * 4 + r) * PPAD + l16;
      QPs[prow +  0] = f2bf1(p0);
      QPs[prow + 16] = f2bf1(p1);
      QPs[prow + 32] = f2bf1(p2);
      QPs[prow + 48] = f2bf1(p3);
    }

#pragma unroll
    for (int s = 0; s < 2; ++s) {
      const short* pr = &QPs[pbase + l16 * PPAD + s * 32 + quad * 8];
      const short4_t plo = *(const short4_t*)pr;
      const short4_t phi = *(const short4_t*)(pr + 4);
      const short8_t pfv = {plo[0], plo[1], plo[2], plo[3], phi[0], phi[1], phi[2], phi[3]};
#pragma unroll
      for (int t = 0; t < 4; ++t) {
        const short8_t vf = *(const short8_t*)&Vsf[(t * 16 + l16) * DPAD + s * 32 + quad * 8];
        oacc[t] = mfma32(pfv, vf, oacc[t]);
      }
    }
    __syncthreads();
  }

  float inv[4];
#pragma unroll
  for (int r = 0; r < 4; ++r) {
    float v = lsumv[r];
    v += __shfl_xor(v, 1);
    v += __shfl_xor(v, 2);
    v += __shfl_xor(v, 4);
    v += __shfl_xor(v, 8);
    inv[r] = 1.0f / v;
  }
#pragma unroll
  for (int t = 0; t < 4; ++t)
#pragma unroll
    for (int r = 0; r < 4; ++r)
      outg[base + (size_t)(t * 16 + l16) * SEQ +
           (size_t)(q0 + w * 16 + quad * 4 + r)] = oacc[t][r] * inv[r];
}

extern "C" void kernel_launch(void* const* d_in, const int* in_sizes, int n_in,
                              void* d_out, int out_size, void* d_ws, size_t ws_size,
                              hipStream_t stream) {
  const float* q  = (const float*)d_in[0];
  const float* k  = (const float*)d_in[1];
  const float* v  = (const float*)d_in[2];
  const int*   kl = (const int*)d_in[3];
  float* out = (float*)d_out;

  const size_t TEN  = (size_t)NBH * SEQ * 64;
  const size_t need = 2 * TEN * sizeof(unsigned short);  // 16.8 MB

  if (ws_size >= need) {
    unsigned short* Kt2 = (unsigned short*)d_ws;
    unsigned short* Vt2 = Kt2 + TEN;
    eia_prep_kernel<<<1024, 256, 0, stream>>>(k, v, Kt2, Vt2);
    eia_attn_kernel<<<512, 512, 0, stream>>>(q, Kt2, Vt2, kl, out);
  } else {
    eia_attn_fb<<<1024, 256, 0, stream>>>(q, k, v, kl, out);
  }
}